// Round 3
// baseline (160.607 us; speedup 1.0000x reference)
//
#include <hip/hip_runtime.h>

#define CROP 14
#define NPOS (CROP * CROP)       // 196
#define CHANNELS 256
#define CPB 128                  // channels per block
#define NCHUNK (CHANNELS / CPB)  // 2
#define NQ (NPOS / 4)            // 49 float4 positions per channel

typedef float __attribute__((ext_vector_type(4))) fx4;
typedef int   __attribute__((ext_vector_type(4))) ix4;

__global__ __launch_bounds__(256) void crop_roi_kernel(
    const float* __restrict__ p2, const float* __restrict__ p3,
    const float* __restrict__ p4, const float* __restrict__ p5,
    const float* __restrict__ props, float* __restrict__ out)
{
    const int blk = blockIdx.x;
    const int n   = blk >> 1;              // proposal index (NCHUNK == 2)
    const int c0  = (blk & 1) * CPB;       // channel chunk base
    const int tid = threadIdx.x;

    // Per-position tables (SoA, 16B aligned so 4-consecutive reads are ds_read_b128)
    __shared__ __attribute__((aligned(16))) int   s_o00[NPOS], s_o01[NPOS], s_o10[NPOS], s_o11[NPOS];
    __shared__ __attribute__((aligned(16))) float s_w00[NPOS], s_w01[NPOS], s_w10[NPOS], s_w11[NPOS];
    __shared__ const float* s_base;
    __shared__ int s_HW;

    if (tid < NPOS) {
        const float bi = props[n * 7 + 0];
        const float x0 = props[n * 7 + 1];
        const float y0 = props[n * 7 + 2];
        const float x1 = props[n * 7 + 3];
        const float y1 = props[n * 7 + 4];

        const float sz = sqrtf((x1 - x0) * (y1 - y0));

        // argmin |sz - base|, first-occurrence tie-break (matches jnp.argmin)
        int lvl = 0;
        float bd = fabsf(sz - 8.0f);
        float d;
        d = fabsf(sz - 16.0f); if (d < bd) { bd = d; lvl = 1; }
        d = fabsf(sz - 32.0f); if (d < bd) { bd = d; lvl = 2; }
        d = fabsf(sz - 64.0f); if (d < bd) { bd = d; lvl = 3; }

        const int   H     = 256 >> lvl;                 // H == W per level
        const float scale = 0.25f / (float)(1 << lvl);  // exact powers of two

        if (tid == 0) {
            const float* fp;
            switch (lvl) {
                case 0:  fp = p2; break;
                case 1:  fp = p3; break;
                case 2:  fp = p4; break;
                default: fp = p5; break;
            }
            s_base = fp + (size_t)((int)bi) * CHANNELS * H * H;
            s_HW   = H * H;
        }

        const int y = tid / CROP;
        const int x = tid - y * CROP;

        // y sample (ref op order: scale first, then lerp with g = i/13)
        const float gy  = (float)y / 13.0f;
        const float ys0 = y0 * scale, ys1 = y1 * scale;
        const float ys  = ys0 + (ys1 - ys0) * gy;
        const float yf  = floorf(ys);
        const float ly  = ys - yf;                       // unclamped frac (ref)
        int yi0 = min(max((int)yf, 0), H - 1);
        const int yi1 = min(yi0 + 1, H - 1);

        // x sample
        const float gx  = (float)x / 13.0f;
        const float xs0 = x0 * scale, xs1 = x1 * scale;
        const float xs  = xs0 + (xs1 - xs0) * gx;
        const float xf  = floorf(xs);
        const float lx  = xs - xf;
        int xi0 = min(max((int)xf, 0), H - 1);
        const int xi1 = min(xi0 + 1, H - 1);

        s_o00[tid] = yi0 * H + xi0;
        s_o01[tid] = yi0 * H + xi1;
        s_o10[tid] = yi1 * H + xi0;
        s_o11[tid] = yi1 * H + xi1;
        const float omy = 1.0f - ly, omx = 1.0f - lx;
        s_w00[tid] = omy * omx;
        s_w01[tid] = omy * lx;
        s_w10[tid] = ly * omx;
        s_w11[tid] = ly * lx;
    }
    __syncthreads();

    const float* __restrict__ base = s_base;
    const int HW = s_HW;
    // float4-aligned: (n*CHANNELS + c0) * NPOS floats; NPOS*4B = 784B = 49*16B
    fx4* __restrict__ out4 =
        reinterpret_cast<fx4*>(out + ((size_t)n * CHANNELS + c0) * NPOS);

    // CPB channels * 49 float4 = 6272 float4s; i walks output contiguously.
    for (int i = tid; i < CPB * NQ; i += 256) {
        const int c = i / NQ;               // magic mul
        const int q = i - c * NQ;           // float4 index within channel
        const int p = q * 4;                // first crop position

        const float* __restrict__ fb = base + (size_t)(c0 + c) * HW;

        const ix4 o00 = *reinterpret_cast<const ix4*>(&s_o00[p]);
        const ix4 o01 = *reinterpret_cast<const ix4*>(&s_o01[p]);
        const ix4 o10 = *reinterpret_cast<const ix4*>(&s_o10[p]);
        const ix4 o11 = *reinterpret_cast<const ix4*>(&s_o11[p]);
        const fx4 w00 = *reinterpret_cast<const fx4*>(&s_w00[p]);
        const fx4 w01 = *reinterpret_cast<const fx4*>(&s_w01[p]);
        const fx4 w10 = *reinterpret_cast<const fx4*>(&s_w10[p]);
        const fx4 w11 = *reinterpret_cast<const fx4*>(&s_w11[p]);

        // 16 independent gathers — issue all loads before consuming
        const float a0 = fb[o00.x], b0 = fb[o01.x], g0 = fb[o10.x], h0 = fb[o11.x];
        const float a1 = fb[o00.y], b1 = fb[o01.y], g1 = fb[o10.y], h1 = fb[o11.y];
        const float a2 = fb[o00.z], b2 = fb[o01.z], g2 = fb[o10.z], h2 = fb[o11.z];
        const float a3 = fb[o00.w], b3 = fb[o01.w], g3 = fb[o10.w], h3 = fb[o11.w];

        fx4 r;
        r.x = a0 * w00.x + b0 * w01.x + g0 * w10.x + h0 * w11.x;
        r.y = a1 * w00.y + b1 * w01.y + g1 * w10.y + h1 * w11.y;
        r.z = a2 * w00.z + b2 * w01.z + g2 * w10.z + h2 * w11.z;
        r.w = a3 * w00.w + b3 * w01.w + g3 * w10.w + h3 * w11.w;

        __builtin_nontemporal_store(r, out4 + i);
    }
}

extern "C" void kernel_launch(void* const* d_in, const int* in_sizes, int n_in,
                              void* d_out, int out_size, void* d_ws, size_t ws_size,
                              hipStream_t stream) {
    const float* p2    = (const float*)d_in[0];
    const float* p3    = (const float*)d_in[1];
    const float* p4    = (const float*)d_in[2];
    const float* p5    = (const float*)d_in[3];
    const float* props = (const float*)d_in[4];
    float* outp        = (float*)d_out;

    const int N = in_sizes[4] / 7;           // 1024 proposals
    dim3 grid(N * NCHUNK);                   // 2048 blocks
    dim3 block(256);
    hipLaunchKernelGGL(crop_roi_kernel, grid, block, 0, stream,
                       p2, p3, p4, p5, props, outp);
}

// Round 4
// 100.325 us; speedup vs baseline: 1.6009x; 1.6009x over previous
//
#include <hip/hip_runtime.h>

#define CROP 14
#define NPOS (CROP * CROP)       // 196
#define CHANNELS 256
#define CPB 64                   // channels per block in idx space
#define CSTRIDE 128              // channel-unroll stride (second channel = c + 128)

__global__ __launch_bounds__(256) void crop_roi_kernel(
    const float* __restrict__ p2, const float* __restrict__ p3,
    const float* __restrict__ p4, const float* __restrict__ p5,
    const float* __restrict__ props, float* __restrict__ out)
{
    const int blk = blockIdx.x;
    const int n   = blk >> 1;              // proposal index
    const int c0  = (blk & 1) * CPB;       // channel chunk base: 0 or 64
    const int tid = threadIdx.x;

    // Per-position tables: corner offsets + bilinear weights.
    // Lanes read consecutive pos -> stride-1 dword LDS reads (conflict-free).
    __shared__ int   s_o00[NPOS], s_o01[NPOS], s_o10[NPOS], s_o11[NPOS];
    __shared__ float s_w00[NPOS], s_w01[NPOS], s_w10[NPOS], s_w11[NPOS];
    __shared__ const float* s_base;
    __shared__ int s_HW;

    if (tid < NPOS) {
        const float bi = props[n * 7 + 0];
        const float x0 = props[n * 7 + 1];
        const float y0 = props[n * 7 + 2];
        const float x1 = props[n * 7 + 3];
        const float y1 = props[n * 7 + 4];

        const float sz = sqrtf((x1 - x0) * (y1 - y0));

        // argmin |sz - base|, first-occurrence tie-break (matches jnp.argmin)
        int lvl = 0;
        float bd = fabsf(sz - 8.0f);
        float d;
        d = fabsf(sz - 16.0f); if (d < bd) { bd = d; lvl = 1; }
        d = fabsf(sz - 32.0f); if (d < bd) { bd = d; lvl = 2; }
        d = fabsf(sz - 64.0f); if (d < bd) { bd = d; lvl = 3; }

        const int   H     = 256 >> lvl;                 // H == W per level
        const float scale = 0.25f / (float)(1 << lvl);  // exact powers of two

        if (tid == 0) {
            const float* fp;
            switch (lvl) {
                case 0:  fp = p2; break;
                case 1:  fp = p3; break;
                case 2:  fp = p4; break;
                default: fp = p5; break;
            }
            s_base = fp + (size_t)((int)bi) * CHANNELS * H * H;
            s_HW   = H * H;
        }

        const int y = tid / CROP;
        const int x = tid - y * CROP;

        // y sample (ref op order: scale first, then lerp with g = i/13)
        const float gy  = (float)y / 13.0f;
        const float ys0 = y0 * scale, ys1 = y1 * scale;
        const float ys  = ys0 + (ys1 - ys0) * gy;
        const float yf  = floorf(ys);
        const float ly  = ys - yf;                       // unclamped frac (ref)
        int yi0 = min(max((int)yf, 0), H - 1);
        const int yi1 = min(yi0 + 1, H - 1);

        // x sample
        const float gx  = (float)x / 13.0f;
        const float xs0 = x0 * scale, xs1 = x1 * scale;
        const float xs  = xs0 + (xs1 - xs0) * gx;
        const float xf  = floorf(xs);
        const float lx  = xs - xf;
        int xi0 = min(max((int)xf, 0), H - 1);
        const int xi1 = min(xi0 + 1, H - 1);

        s_o00[tid] = yi0 * H + xi0;
        s_o01[tid] = yi0 * H + xi1;
        s_o10[tid] = yi1 * H + xi0;
        s_o11[tid] = yi1 * H + xi1;
        const float omy = 1.0f - ly, omx = 1.0f - lx;
        s_w00[tid] = omy * omx;
        s_w01[tid] = omy * lx;
        s_w10[tid] = ly * omx;
        s_w11[tid] = ly * lx;
    }
    __syncthreads();

    const float* __restrict__ base = s_base;
    const int HW = s_HW;
    // This block writes channels [c0, c0+64) and [c0+128, c0+192).
    float* __restrict__ outp = out + ((size_t)n * CHANNELS + c0) * NPOS;

    // 64 channels * 196 positions; idx walks output contiguously.
    // Consecutive lanes -> consecutive pos: gathers cluster within a row,
    // stores are 256B-contiguous per wave, LDS reads are stride-1/broadcast.
    for (int idx = tid; idx < CPB * NPOS; idx += 256) {
        const int c   = idx / NPOS;           // magic mul
        const int pos = idx - c * NPOS;

        const float* __restrict__ fb1 = base + (size_t)(c0 + c) * HW;
        const float* __restrict__ fb2 = fb1 + (size_t)CSTRIDE * HW;

        const int   o00 = s_o00[pos];
        const int   o01 = s_o01[pos];
        const int   o10 = s_o10[pos];
        const int   o11 = s_o11[pos];
        const float w00 = s_w00[pos];
        const float w01 = s_w01[pos];
        const float w10 = s_w10[pos];
        const float w11 = s_w11[pos];

        // 8 independent gathers in flight
        const float a1 = fb1[o00], b1 = fb1[o01], g1 = fb1[o10], h1 = fb1[o11];
        const float a2 = fb2[o00], b2 = fb2[o01], g2 = fb2[o10], h2 = fb2[o11];

        const float r1 = a1 * w00 + b1 * w01 + g1 * w10 + h1 * w11;
        const float r2 = a2 * w00 + b2 * w01 + g2 * w10 + h2 * w11;

        outp[idx]                          = r1;
        outp[idx + (size_t)CSTRIDE * NPOS] = r2;
    }
}

extern "C" void kernel_launch(void* const* d_in, const int* in_sizes, int n_in,
                              void* d_out, int out_size, void* d_ws, size_t ws_size,
                              hipStream_t stream) {
    const float* p2    = (const float*)d_in[0];
    const float* p3    = (const float*)d_in[1];
    const float* p4    = (const float*)d_in[2];
    const float* p5    = (const float*)d_in[3];
    const float* props = (const float*)d_in[4];
    float* outp        = (float*)d_out;

    const int N = in_sizes[4] / 7;           // 1024 proposals
    dim3 grid(N * 2);                        // 2048 blocks
    dim3 block(256);
    hipLaunchKernelGGL(crop_roi_kernel, grid, block, 0, stream,
                       p2, p3, p4, p5, props, outp);
}